// Round 1
// baseline (528.050 us; speedup 1.0000x reference)
//
#include <hip/hip_runtime.h>
#include <stdint.h>

// ---------- types ----------
using s8v  = __attribute__((ext_vector_type(8))) short;    // 8 bf16 (A/B frag)
using f4   = __attribute__((ext_vector_type(4))) float;    // C/D frag
using u32x4 = __attribute__((ext_vector_type(4))) uint32_t;
using u32x2 = __attribute__((ext_vector_type(2))) uint32_t;
using vf4  = __attribute__((ext_vector_type(4))) float;

typedef unsigned short ushortT;

// bf16 round-to-nearest-even
static __device__ __forceinline__ uint32_t bfr16(float f) {
  union { float f; uint32_t u; } v; v.f = f;
  return (v.u + 0x7FFFu + ((v.u >> 16) & 1u)) >> 16;
}
static __device__ __forceinline__ uint32_t pk2(float lo, float hi) {
  return (bfr16(hi) << 16) | (bfr16(lo) & 0xFFFFu);
}
// async global->LDS, 16B per lane, LDS dest = uniform base + lane*16
static __device__ __forceinline__ void gl16(const void* g, void* l) {
  __builtin_amdgcn_global_load_lds((const __attribute__((address_space(1))) uint32_t*)g,
                                   (__attribute__((address_space(3))) uint32_t*)l, 16, 0, 0);
}

#define MFMA_BF16(A, B, C) __builtin_amdgcn_mfma_f32_16x16x32_bf16((A), (B), (C), 0, 0, 0)

// problem constants
#define BATCH 8
#define NROW  4096           // H*W
#define CIN   512
#define CQK   64
#define MROWS (BATCH * NROW) // 32768

// ---------------------------------------------------------------------------
// Kernel 0: weights -> bf16, transposed: Wt[640][512]; cols 0-63 Wg, 64-127 Wf,
// 128-639 Wh.  (k-major rows so GEMM B-fragments are contiguous 16B reads.)
// ---------------------------------------------------------------------------
__global__ __launch_bounds__(64) void kprep(const float* __restrict__ Wg,
                                            const float* __restrict__ Wf,
                                            const float* __restrict__ Wh,
                                            ushortT* __restrict__ Wt) {
  const int cIdx = blockIdx.x;     // 0..639
  const int t = threadIdx.x;       // 64
  const float* src; int co, ldc;
  if (cIdx < 64)       { src = Wg; co = cIdx;       ldc = 64;  }
  else if (cIdx < 128) { src = Wf; co = cIdx - 64;  ldc = 64;  }
  else                 { src = Wh; co = cIdx - 128; ldc = 512; }
#pragma unroll
  for (int kk = 0; kk < 8; ++kk) {
    int k = kk * 64 + t;
    Wt[(size_t)cIdx * 512 + k] = (ushortT)bfr16(src[(size_t)k * ldc + co]);
  }
}

// ---------------------------------------------------------------------------
// Kernel 1: projection GEMM.  out[row, col] = x[row,:] @ W[:,col] + bias.
// grid = (10 col-tiles, 512 row-tiles), 256 threads (4 waves).
// col-tile 0 -> Q (bf16 [32768][64]); 1 -> K (same); 2..9 -> Vt (bf16,
// TRANSPOSED: Vt[b][vcol][n]).
// LDS tiles XOR-swizzled (chunk16 ^= row&7) for conflict-free b128 frag reads.
// ---------------------------------------------------------------------------
__global__ __launch_bounds__(256) void kproj(const float* __restrict__ x,
                                             const ushortT* __restrict__ Wt,
                                             const float* __restrict__ bg,
                                             const float* __restrict__ bfv,
                                             const float* __restrict__ bh,
                                             ushortT* __restrict__ Q,
                                             ushortT* __restrict__ K,
                                             ushortT* __restrict__ Vt) {
  __shared__ ushortT Al[64 * 64];   // x tile  [row][k]  8KB swizzled
  __shared__ ushortT Bl[64 * 64];   // Wt tile [col][k]  8KB swizzled

  const int tid = threadIdx.x;
  const int w = tid >> 6, l = tid & 63, h = l >> 4, c = l & 15;
  const int ct = blockIdx.x, rt = blockIdx.y;
  const int row0 = rt * 64;

  f4 acc[4];
#pragma unroll
  for (int j = 0; j < 4; ++j) acc[j] = (f4){0.f, 0.f, 0.f, 0.f};

  const int arow = tid >> 2, aseg = tid & 3;
  const float* xrow = x + (size_t)(row0 + arow) * 512 + aseg * 16;

  for (int kk = 0; kk < 8; ++kk) {
    const int k0 = kk * 64;
    // ---- stage A: 16 fp32 -> 16 bf16, 2 swizzled b128 writes
    vf4 f0 = *(const vf4*)(xrow + k0 + 0);
    vf4 f1 = *(const vf4*)(xrow + k0 + 4);
    vf4 f2 = *(const vf4*)(xrow + k0 + 8);
    vf4 f3 = *(const vf4*)(xrow + k0 + 12);
    u32x4 ch0 = { pk2(f0[0], f0[1]), pk2(f0[2], f0[3]), pk2(f1[0], f1[1]), pk2(f1[2], f1[3]) };
    u32x4 ch1 = { pk2(f2[0], f2[1]), pk2(f2[2], f2[3]), pk2(f3[0], f3[1]), pk2(f3[2], f3[3]) };
    const int sw = arow & 7;
    *(u32x4*)((char*)Al + arow * 128 + (((aseg * 2 + 0) ^ sw) * 16)) = ch0;
    *(u32x4*)((char*)Al + arow * 128 + (((aseg * 2 + 1) ^ sw) * 16)) = ch1;
    // ---- stage B: global_load_lds, source pre-swizzled so LDS stays linear
#pragma unroll
    for (int j = 0; j < 2; ++j) {
      const int col = w * 16 + j * 8 + (l >> 3);
      const int c7 = l & 7;
      const ushortT* src = Wt + (size_t)(ct * 64 + col) * 512 + k0 + 8 * (c7 ^ (l >> 3));
      gl16(src, (char*)Bl + (w * 128 + j * 64) * 16);
    }
    __syncthreads();   // staging (ds_write + global_load_lds) complete
    // ---- MFMA: wave w owns rows w*16..w*16+15, all 64 cols
#pragma unroll
    for (int ks = 0; ks < 2; ++ks) {
      s8v af = *(const s8v*)((char*)Al + (w * 16 + c) * 128 + (((ks * 4 + h) ^ (c & 7)) * 16));
#pragma unroll
      for (int cj = 0; cj < 4; ++cj) {
        s8v bf8 = *(const s8v*)((char*)Bl + (cj * 16 + c) * 128 + (((ks * 4 + h) ^ (c & 7)) * 16));
        acc[cj] = MFMA_BF16(af, bf8, acc[cj]);
      }
    }
    __syncthreads();   // reads done before next-iter restage
  }

  // ---- epilogue: bias + store
  const int colbase = ct * 64;
  const float* bias = (ct == 0) ? bg : (ct == 1) ? bfv : bh;
  const int bo = (ct < 2) ? 0 : (colbase - 128);
  const int rbase = row0 + w * 16 + h * 4;
  if (ct < 2) {
    ushortT* dst = (ct == 0) ? Q : K;
#pragma unroll
    for (int cj = 0; cj < 4; ++cj) {
      const int cl = cj * 16 + c;
      const float bv = bias[cl];
#pragma unroll
      for (int r = 0; r < 4; ++r)
        dst[(size_t)(rbase + r) * 64 + cl] = (ushortT)bfr16(acc[cj][r] + bv);
    }
  } else {
    const int b = row0 >> 12;
    const int n0 = (row0 & 4095) + w * 16 + h * 4;
#pragma unroll
    for (int cj = 0; cj < 4; ++cj) {
      const int cl = cj * 16 + c;
      const float bv = bias[bo + cl];
      const int vcol = bo + cl;
      u32x2 dd = { pk2(acc[cj][0] + bv, acc[cj][1] + bv),
                   pk2(acc[cj][2] + bv, acc[cj][3] + bv) };
      *(u32x2*)(Vt + (size_t)(b * 512 + vcol) * 4096 + n0) = dd;  // transposed store
    }
  }
}

// ---------------------------------------------------------------------------
// Kernel 2: flash attention + fused epilogue  out = gamma*(O/l) + x.
// grid = 512 (b = blk>>6, qtile = blk&63), 512 threads (8 waves).
// QBLK=64 (shared), KVBLK=32.  Waves 0-3: S^T = mfma(K,Q) for q-block w,
// in-register online softmax (lane col == q), scatter P into fragment-major
// LDS.  All 8 waves: PV over own 64 V-columns from swizzled Vt tile.
// ---------------------------------------------------------------------------
__global__ __launch_bounds__(512) void kattn(const ushortT* __restrict__ Qg,
                                             const ushortT* __restrict__ Kg,
                                             const ushortT* __restrict__ Vtg,
                                             const float* __restrict__ x,
                                             const float* __restrict__ gamma,
                                             float* __restrict__ out) {
  __shared__ ushortT Kl[32 * 64];      // 4KB  [kv][d], chunk16 ^= kv&7
  __shared__ ushortT Vl[512 * 32];     // 32KB [vcol][kv], chunk16 ^= vcol&3
  __shared__ uint32_t Pl[4 * 64 * 4];  // 4KB  frag-major: (qi*64+lane)*4+g
  __shared__ float alpha_s[64];
  __shared__ float lsum_s[64];

  const int tid = threadIdx.x;
  const int w = tid >> 6, l = tid & 63, h = l >> 4, c = l & 15;
  const int bb = blockIdx.x >> 6, qb = blockIdx.x & 63;
  const size_t qrow0 = (size_t)bb * 4096 + (size_t)qb * 64;

  f4 acc[4][4];
#pragma unroll
  for (int qi = 0; qi < 4; ++qi)
#pragma unroll
    for (int vj = 0; vj < 4; ++vj) acc[qi][vj] = (f4){0.f, 0.f, 0.f, 0.f};

  // Q fragments for S-waves (B-operand of S^T): q = w*16 + c
  s8v qf[2];
  if (w < 4) {
#pragma unroll
    for (int ks = 0; ks < 2; ++ks)
      qf[ks] = *(const s8v*)(Qg + (qrow0 + w * 16 + c) * 64 + ks * 32 + h * 8);
  }
  float m_run = -__builtin_inff();
  float l_run = 0.0f;

  const ushortT* Kb = Kg + (size_t)bb * 4096 * 64;
  const ushortT* Vb = Vtg + (size_t)bb * 512 * 4096;

  for (int t = 0; t < 128; ++t) {
    __syncthreads();  // (1) prior-iter LDS reads done before restaging
    // ---- stage K tile [32][64]: waves 0-3, one gl16 each (src pre-swizzled)
    if (w < 4) {
      const int kv = w * 8 + (l >> 3), c7 = l & 7;
      gl16(Kb + ((size_t)t * 32 + kv) * 64 + 8 * (c7 ^ (l >> 3)),
           (char*)Kl + (w * 64) * 16);
    }
    // ---- stage V tile [512][32]: all waves, 4 gl16 each
#pragma unroll
    for (int i = 0; i < 4; ++i) {
      const int vcol = (w * 4 + i) * 16 + (l >> 2);
      const int c4 = l & 3;
      gl16(Vb + (size_t)vcol * 4096 + t * 32 + 8 * (c4 ^ ((l >> 2) & 3)),
           (char*)Vl + ((w * 4 + i) * 64) * 16);
    }
    __syncthreads();  // (2) staging arrived (vmcnt drained by barrier)

    // ---- S^T + online softmax (waves 0-3; wave w owns q-block w)
    if (w < 4) {
      f4 sacc[2] = { (f4){0.f,0.f,0.f,0.f}, (f4){0.f,0.f,0.f,0.f} };
#pragma unroll
      for (int kj = 0; kj < 2; ++kj)
#pragma unroll
        for (int ks = 0; ks < 2; ++ks) {
          s8v kf = *(const s8v*)((char*)Kl + (kj * 16 + c) * 128 +
                                 (((ks * 4 + h) ^ (c & 7)) * 16));
          sacc[kj] = MFMA_BF16(kf, qf[ks], sacc[kj]);  // D[kv, q]
        }
      // row (=q) reduce: in-lane over 8 + cross-h (masks 16, 32)
      float tm = sacc[0][0];
#pragma unroll
      for (int r = 1; r < 4; ++r) tm = fmaxf(tm, sacc[0][r]);
#pragma unroll
      for (int r = 0; r < 4; ++r) tm = fmaxf(tm, sacc[1][r]);
      tm = fmaxf(tm, __shfl_xor(tm, 16));
      tm = fmaxf(tm, __shfl_xor(tm, 32));
      const float m_new = fmaxf(m_run, tm);
      const float al = __expf(m_run - m_new);   // 0 on first tile
      float p[2][4]; float ts = 0.f;
#pragma unroll
      for (int kj = 0; kj < 2; ++kj)
#pragma unroll
        for (int r = 0; r < 4; ++r) {
          p[kj][r] = __expf(sacc[kj][r] - m_new);
          ts += p[kj][r];
        }
      ts += __shfl_xor(ts, 16);
      ts += __shfl_xor(ts, 32);
      l_run = l_run * al + ts;
      m_run = m_new;
      // scatter P -> fragment-major A-layout:
      // src (kj, h, i) -> lane' = c + 16*(kj*2 + (h>>1)), reg = (h&1)*2 + i
#pragma unroll
      for (int kj = 0; kj < 2; ++kj)
#pragma unroll
        for (int i = 0; i < 2; ++i) {
          const uint32_t pw = pk2(p[kj][2 * i], p[kj][2 * i + 1]);
          const int dw = (w * 64 + c + 16 * (kj * 2 + (h >> 1))) * 4 + (h & 1) * 2 + i;
          Pl[dw] = pw;
        }
      if (h == 0) alpha_s[w * 16 + c] = al;
    }

    // ---- V fragments (all waves; overlaps S phase for waves 4-7)
    s8v vfr[4];
#pragma unroll
    for (int vj = 0; vj < 4; ++vj) {
      const int vcol = w * 64 + vj * 16 + c;
      vfr[vj] = *(const s8v*)((char*)Vl + vcol * 64 + ((h ^ (vcol & 3)) * 16));
    }
    __syncthreads();  // (3) P + alpha ready

    // ---- rescale accumulators, then PV MFMAs
#pragma unroll
    for (int qi = 0; qi < 4; ++qi) {
      f4 a4 = *(const f4*)(&alpha_s[qi * 16 + h * 4]);
#pragma unroll
      for (int vj = 0; vj < 4; ++vj)
#pragma unroll
        for (int r = 0; r < 4; ++r) acc[qi][vj][r] *= a4[r];
    }
#pragma unroll
    for (int qi = 0; qi < 4; ++qi) {
      s8v pa = *(const s8v*)(&Pl[(qi * 64 + l) * 4]);
#pragma unroll
      for (int vj = 0; vj < 4; ++vj)
        acc[qi][vj] = MFMA_BF16(pa, vfr[vj], acc[qi][vj]);
    }
  }

  // ---- finalize: out = gamma * (acc / l) + x
  if (w < 4 && h == 0) lsum_s[w * 16 + c] = l_run;
  __syncthreads();
#pragma unroll
  for (int qi = 0; qi < 4; ++qi) {
    f4 l4 = *(const f4*)(&lsum_s[qi * 16 + h * 4]);
#pragma unroll
    for (int vj = 0; vj < 4; ++vj) {
      const int colg = w * 64 + vj * 16 + c;
      const float gm = gamma[colg];
#pragma unroll
      for (int r = 0; r < 4; ++r) {
        const size_t idx = (qrow0 + qi * 16 + h * 4 + r) * 512 + colg;
        out[idx] = gm * (acc[qi][vj][r] / l4[r]) + x[idx];
      }
    }
  }
}

// ---------------------------------------------------------------------------
extern "C" void kernel_launch(void* const* d_in, const int* in_sizes, int n_in,
                              void* d_out, int out_size, void* d_ws, size_t ws_size,
                              hipStream_t stream) {
  const float* x     = (const float*)d_in[0];
  const float* Wg    = (const float*)d_in[1];
  const float* bg    = (const float*)d_in[2];
  const float* Wf    = (const float*)d_in[3];
  const float* bfv   = (const float*)d_in[4];
  const float* Wh    = (const float*)d_in[5];
  const float* bh    = (const float*)d_in[6];
  const float* gamma = (const float*)d_in[7];
  float* out = (float*)d_out;
  char* ws = (char*)d_ws;

  // workspace layout (bytes): Q 4Mi | K 4Mi | Vt 32Mi | Wt 640KiB  (~42.6 MiB)
  ushortT* Q  = (ushortT*)(ws);
  ushortT* K  = (ushortT*)(ws + ((size_t)4 << 20));
  ushortT* Vt = (ushortT*)(ws + ((size_t)8 << 20));
  ushortT* Wt = (ushortT*)(ws + ((size_t)40 << 20));

  kprep<<<dim3(640), dim3(64), 0, stream>>>(Wg, Wf, Wh, Wt);
  kproj<<<dim3(10, 512), dim3(256), 0, stream>>>(x, Wt, bg, bfv, bh, Q, K, Vt);
  kattn<<<dim3(512), dim3(512), 0, stream>>>(Q, K, Vt, x, gamma, out);
}

// Round 2
// 449.188 us; speedup vs baseline: 1.1756x; 1.1756x over previous
//
#include <hip/hip_runtime.h>
#include <stdint.h>

// ---------- types ----------
using s8v  = __attribute__((ext_vector_type(8))) short;    // 8 bf16 (A/B frag)
using f4   = __attribute__((ext_vector_type(4))) float;    // C/D frag
using u32x4 = __attribute__((ext_vector_type(4))) uint32_t;
using u32x2 = __attribute__((ext_vector_type(2))) uint32_t;
using vf4  = __attribute__((ext_vector_type(4))) float;

typedef unsigned short ushortT;

// bf16 round-to-nearest-even
static __device__ __forceinline__ uint32_t bfr16(float f) {
  union { float f; uint32_t u; } v; v.f = f;
  return (v.u + 0x7FFFu + ((v.u >> 16) & 1u)) >> 16;
}
static __device__ __forceinline__ uint32_t pk2(float lo, float hi) {
  return (bfr16(hi) << 16) | (bfr16(lo) & 0xFFFFu);
}
// async global->LDS, 16B per lane, LDS dest = wave-uniform base + lane*16
static __device__ __forceinline__ void gl16(const void* g, void* l) {
  __builtin_amdgcn_global_load_lds((const __attribute__((address_space(1))) uint32_t*)g,
                                   (__attribute__((address_space(3))) uint32_t*)l, 16, 0, 0);
}

#define MFMA_BF16(A, B, C) __builtin_amdgcn_mfma_f32_16x16x32_bf16((A), (B), (C), 0, 0, 0)

// ---------------------------------------------------------------------------
// Kernel 0: weights -> bf16, transposed: Wt[640][512]; cols 0-63 Wg, 64-127 Wf,
// 128-639 Wh.
// ---------------------------------------------------------------------------
__global__ __launch_bounds__(64) void kprep(const float* __restrict__ Wg,
                                            const float* __restrict__ Wf,
                                            const float* __restrict__ Wh,
                                            ushortT* __restrict__ Wt) {
  const int cIdx = blockIdx.x;     // 0..639
  const int t = threadIdx.x;       // 64
  const float* src; int co, ldc;
  if (cIdx < 64)       { src = Wg; co = cIdx;       ldc = 64;  }
  else if (cIdx < 128) { src = Wf; co = cIdx - 64;  ldc = 64;  }
  else                 { src = Wh; co = cIdx - 128; ldc = 512; }
#pragma unroll
  for (int kk = 0; kk < 8; ++kk) {
    int k = kk * 64 + t;
    Wt[(size_t)cIdx * 512 + k] = (ushortT)bfr16(src[(size_t)k * ldc + co]);
  }
}

// ---------------------------------------------------------------------------
// Kernel 1: projection GEMM (unchanged from round 1).
// ---------------------------------------------------------------------------
__global__ __launch_bounds__(256) void kproj(const float* __restrict__ x,
                                             const ushortT* __restrict__ Wt,
                                             const float* __restrict__ bg,
                                             const float* __restrict__ bfv,
                                             const float* __restrict__ bh,
                                             ushortT* __restrict__ Q,
                                             ushortT* __restrict__ K,
                                             ushortT* __restrict__ Vt) {
  __shared__ ushortT Al[64 * 64];
  __shared__ ushortT Bl[64 * 64];

  const int tid = threadIdx.x;
  const int w = tid >> 6, l = tid & 63, h = l >> 4, c = l & 15;
  const int ct = blockIdx.x, rt = blockIdx.y;
  const int row0 = rt * 64;

  f4 acc[4];
#pragma unroll
  for (int j = 0; j < 4; ++j) acc[j] = (f4){0.f, 0.f, 0.f, 0.f};

  const int arow = tid >> 2, aseg = tid & 3;
  const float* xrow = x + (size_t)(row0 + arow) * 512 + aseg * 16;

  for (int kk = 0; kk < 8; ++kk) {
    const int k0 = kk * 64;
    vf4 f0 = *(const vf4*)(xrow + k0 + 0);
    vf4 f1 = *(const vf4*)(xrow + k0 + 4);
    vf4 f2 = *(const vf4*)(xrow + k0 + 8);
    vf4 f3 = *(const vf4*)(xrow + k0 + 12);
    u32x4 ch0 = { pk2(f0[0], f0[1]), pk2(f0[2], f0[3]), pk2(f1[0], f1[1]), pk2(f1[2], f1[3]) };
    u32x4 ch1 = { pk2(f2[0], f2[1]), pk2(f2[2], f2[3]), pk2(f3[0], f3[1]), pk2(f3[2], f3[3]) };
    const int sw = arow & 7;
    *(u32x4*)((char*)Al + arow * 128 + (((aseg * 2 + 0) ^ sw) * 16)) = ch0;
    *(u32x4*)((char*)Al + arow * 128 + (((aseg * 2 + 1) ^ sw) * 16)) = ch1;
#pragma unroll
    for (int j = 0; j < 2; ++j) {
      const int col = w * 16 + j * 8 + (l >> 3);
      const int c7 = l & 7;
      const ushortT* src = Wt + (size_t)(ct * 64 + col) * 512 + k0 + 8 * (c7 ^ (l >> 3));
      gl16(src, (char*)Bl + (w * 128 + j * 64) * 16);
    }
    __syncthreads();
#pragma unroll
    for (int ks = 0; ks < 2; ++ks) {
      s8v af = *(const s8v*)((char*)Al + (w * 16 + c) * 128 + (((ks * 4 + h) ^ (c & 7)) * 16));
#pragma unroll
      for (int cj = 0; cj < 4; ++cj) {
        s8v bf8 = *(const s8v*)((char*)Bl + (cj * 16 + c) * 128 + (((ks * 4 + h) ^ (c & 7)) * 16));
        acc[cj] = MFMA_BF16(af, bf8, acc[cj]);
      }
    }
    __syncthreads();
  }

  const int colbase = ct * 64;
  const float* bias = (ct == 0) ? bg : (ct == 1) ? bfv : bh;
  const int bo = (ct < 2) ? 0 : (colbase - 128);
  const int rbase = row0 + w * 16 + h * 4;
  if (ct < 2) {
    ushortT* dst = (ct == 0) ? Q : K;
#pragma unroll
    for (int cj = 0; cj < 4; ++cj) {
      const int cl = cj * 16 + c;
      const float bv = bias[cl];
#pragma unroll
      for (int r = 0; r < 4; ++r)
        dst[(size_t)(rbase + r) * 64 + cl] = (ushortT)bfr16(acc[cj][r] + bv);
    }
  } else {
    const int b = row0 >> 12;
    const int n0 = (row0 & 4095) + w * 16 + h * 4;
#pragma unroll
    for (int cj = 0; cj < 4; ++cj) {
      const int cl = cj * 16 + c;
      const float bv = bias[bo + cl];
      const int vcol = bo + cl;
      u32x2 dd = { pk2(acc[cj][0] + bv, acc[cj][1] + bv),
                   pk2(acc[cj][2] + bv, acc[cj][3] + bv) };
      *(u32x2*)(Vt + (size_t)(b * 512 + vcol) * 4096 + n0) = dd;
    }
  }
}

// ---------------------------------------------------------------------------
// Kernel 2: flash attention, double-buffered LDS + counted vmcnt pipeline.
// grid = 512 (bb = blk&7 -> XCD-local batch, qb = blk>>3), 512 threads.
// Per tile (KVBLK=32): stage(t+1) async -> vmcnt(5/4) -> B1 -> S+softmax+P
// (waves 0-3) / V-frag ds_reads (all) -> lgkmcnt(0) -> B2 -> rescale+PV.
// ---------------------------------------------------------------------------
__global__ __launch_bounds__(512) void kattn(const ushortT* __restrict__ Qg,
                                             const ushortT* __restrict__ Kg,
                                             const ushortT* __restrict__ Vtg,
                                             const float* __restrict__ x,
                                             const float* __restrict__ gamma,
                                             float* __restrict__ out) {
  __shared__ ushortT Kl[2][32 * 64];      // 8KB  [kv][d], chunk16 ^= kv&7
  __shared__ ushortT Vl[2][512 * 32];     // 64KB [vcol][kv], chunk16 ^= vcol&3
  __shared__ uint32_t Pl[4 * 64 * 4];     // 4KB  frag-major
  __shared__ __align__(16) float alpha_s[64];
  __shared__ __align__(16) float lsum_s[64];

  const int tid = threadIdx.x;
  const int w = tid >> 6, l = tid & 63, h = l >> 4, c = l & 15;
  const int bb = blockIdx.x & 7, qb = blockIdx.x >> 3;   // XCD-aware swizzle
  const size_t qrow0 = (size_t)bb * 4096 + (size_t)qb * 64;

  f4 acc[4][4];
#pragma unroll
  for (int qi = 0; qi < 4; ++qi)
#pragma unroll
    for (int vj = 0; vj < 4; ++vj) acc[qi][vj] = (f4){0.f, 0.f, 0.f, 0.f};

  const ushortT* Kb = Kg + (size_t)bb * 4096 * 64;
  const ushortT* Vb = Vtg + (size_t)bb * 512 * 4096;

  // Q fragments for S-waves (B-operand of S^T): q = w*16 + c
  s8v qf[2];
  if (w < 4) {
#pragma unroll
    for (int ks = 0; ks < 2; ++ks)
      qf[ks] = *(const s8v*)(Qg + (qrow0 + w * 16 + c) * 64 + ks * 32 + h * 8);
  }
  // drain qf so only gl16s are outstanding inside the loop (vmcnt counting)
  asm volatile("s_waitcnt vmcnt(0)" ::: "memory");

  // per-lane staging source pointers (pre-swizzled), advanced per tile
  const ushortT* kap = Kb + (size_t)(w * 8 + (l >> 3)) * 64 + 8 * ((l & 7) ^ (l >> 3));
  const uint32_t vsw = 8u * ((l & 3) ^ ((l >> 2) & 3));
  const ushortT* vap0 = Vb + (size_t)((w * 4 + 0) * 16 + (l >> 2)) * 4096 + vsw;
  const ushortT* vap1 = Vb + (size_t)((w * 4 + 1) * 16 + (l >> 2)) * 4096 + vsw;
  const ushortT* vap2 = Vb + (size_t)((w * 4 + 2) * 16 + (l >> 2)) * 4096 + vsw;
  const ushortT* vap3 = Vb + (size_t)((w * 4 + 3) * 16 + (l >> 2)) * 4096 + vsw;

  // prologue: stage tile 0 into buffer 0
  if (w < 4) { gl16(kap, (char*)Kl[0] + w * 1024); kap += 2048; }
  gl16(vap0, (char*)Vl[0] + (w * 4 + 0) * 1024); vap0 += 32;
  gl16(vap1, (char*)Vl[0] + (w * 4 + 1) * 1024); vap1 += 32;
  gl16(vap2, (char*)Vl[0] + (w * 4 + 2) * 1024); vap2 += 32;
  gl16(vap3, (char*)Vl[0] + (w * 4 + 3) * 1024); vap3 += 32;

  float m_run = -__builtin_inff();
  float l_run = 0.0f;

  for (int t = 0; t < 128; ++t) {
    const int cur = t & 1;
    if (t < 127) {
      // ---- issue stage(t+1) into the other buffer (stays in flight past B1)
      if (w < 4) { gl16(kap, (char*)Kl[cur ^ 1] + w * 1024); kap += 2048; }
      gl16(vap0, (char*)Vl[cur ^ 1] + (w * 4 + 0) * 1024); vap0 += 32;
      gl16(vap1, (char*)Vl[cur ^ 1] + (w * 4 + 1) * 1024); vap1 += 32;
      gl16(vap2, (char*)Vl[cur ^ 1] + (w * 4 + 2) * 1024); vap2 += 32;
      gl16(vap3, (char*)Vl[cur ^ 1] + (w * 4 + 3) * 1024); vap3 += 32;
      // counted wait: tile t's loads (the older 5/4) have landed
      if (w < 4) asm volatile("s_waitcnt vmcnt(5)" ::: "memory");
      else       asm volatile("s_waitcnt vmcnt(4)" ::: "memory");
    } else {
      asm volatile("s_waitcnt vmcnt(0)" ::: "memory");
    }
    __builtin_amdgcn_s_barrier();   // B1: tile t visible to all waves

    // ---- V fragments from Vl[cur] (all waves, issued early)
    s8v vfr[4];
#pragma unroll
    for (int vj = 0; vj < 4; ++vj) {
      const int vcol = w * 64 + vj * 16 + c;
      vfr[vj] = *(const s8v*)((char*)Vl[cur] + vcol * 64 + ((h ^ (vcol & 3)) * 16));
    }

    // ---- S^T + online softmax (waves 0-3; wave w owns q-block w)
    if (w < 4) {
      f4 sacc[2] = { (f4){0.f,0.f,0.f,0.f}, (f4){0.f,0.f,0.f,0.f} };
      __builtin_amdgcn_s_setprio(1);
#pragma unroll
      for (int kj = 0; kj < 2; ++kj)
#pragma unroll
        for (int ks = 0; ks < 2; ++ks) {
          s8v kf = *(const s8v*)((char*)Kl[cur] + (kj * 16 + c) * 128 +
                                 (((ks * 4 + h) ^ (c & 7)) * 16));
          sacc[kj] = MFMA_BF16(kf, qf[ks], sacc[kj]);  // D[kv, q]
        }
      __builtin_amdgcn_s_setprio(0);
      float tm = sacc[0][0];
#pragma unroll
      for (int r = 1; r < 4; ++r) tm = fmaxf(tm, sacc[0][r]);
#pragma unroll
      for (int r = 0; r < 4; ++r) tm = fmaxf(tm, sacc[1][r]);
      tm = fmaxf(tm, __shfl_xor(tm, 16));
      tm = fmaxf(tm, __shfl_xor(tm, 32));
      const float m_new = fmaxf(m_run, tm);
      const float al = __expf(m_run - m_new);   // 0 on first tile
      float p[2][4]; float ts = 0.f;
#pragma unroll
      for (int kj = 0; kj < 2; ++kj)
#pragma unroll
        for (int r = 0; r < 4; ++r) {
          p[kj][r] = __expf(sacc[kj][r] - m_new);
          ts += p[kj][r];
        }
      ts += __shfl_xor(ts, 16);
      ts += __shfl_xor(ts, 32);
      l_run = l_run * al + ts;
      m_run = m_new;
      // scatter P -> fragment-major A-layout
#pragma unroll
      for (int kj = 0; kj < 2; ++kj)
#pragma unroll
        for (int i = 0; i < 2; ++i) {
          const uint32_t pw = pk2(p[kj][2 * i], p[kj][2 * i + 1]);
          const int dw = (w * 64 + c + 16 * (kj * 2 + (h >> 1))) * 4 + (h & 1) * 2 + i;
          Pl[dw] = pw;
        }
      if (h == 0) alpha_s[w * 16 + c] = al;
    }

    // release: P/alpha committed, vfr data landed in regs (protects buffers)
    asm volatile("s_waitcnt lgkmcnt(0)" ::: "memory");
    __builtin_amdgcn_s_barrier();   // B2

    // ---- rescale accumulators, then PV MFMAs
#pragma unroll
    for (int qi = 0; qi < 4; ++qi) {
      f4 a4 = *(const f4*)(&alpha_s[qi * 16 + h * 4]);
#pragma unroll
      for (int vj = 0; vj < 4; ++vj)
#pragma unroll
        for (int r = 0; r < 4; ++r) acc[qi][vj][r] *= a4[r];
    }
    __builtin_amdgcn_s_setprio(1);
#pragma unroll
    for (int qi = 0; qi < 4; ++qi) {
      s8v pa = *(const s8v*)(&Pl[(qi * 64 + l) * 4]);
#pragma unroll
      for (int vj = 0; vj < 4; ++vj)
        acc[qi][vj] = MFMA_BF16(pa, vfr[vj], acc[qi][vj]);
    }
    __builtin_amdgcn_s_setprio(0);
  }

  // ---- finalize: out = gamma * (acc / l) + x
  if (w < 4 && h == 0) lsum_s[w * 16 + c] = l_run;
  __syncthreads();
#pragma unroll
  for (int qi = 0; qi < 4; ++qi) {
    f4 l4 = *(const f4*)(&lsum_s[qi * 16 + h * 4]);
#pragma unroll
    for (int vj = 0; vj < 4; ++vj) {
      const int colg = w * 64 + vj * 16 + c;
      const float gm = gamma[colg];
#pragma unroll
      for (int r = 0; r < 4; ++r) {
        const size_t idx = (qrow0 + qi * 16 + h * 4 + r) * 512 + colg;
        out[idx] = gm * (acc[qi][vj][r] / l4[r]) + x[idx];
      }
    }
  }
}

// ---------------------------------------------------------------------------
extern "C" void kernel_launch(void* const* d_in, const int* in_sizes, int n_in,
                              void* d_out, int out_size, void* d_ws, size_t ws_size,
                              hipStream_t stream) {
  const float* x     = (const float*)d_in[0];
  const float* Wg    = (const float*)d_in[1];
  const float* bg    = (const float*)d_in[2];
  const float* Wf    = (const float*)d_in[3];
  const float* bfv   = (const float*)d_in[4];
  const float* Wh    = (const float*)d_in[5];
  const float* bh    = (const float*)d_in[6];
  const float* gamma = (const float*)d_in[7];
  float* out = (float*)d_out;
  char* ws = (char*)d_ws;

  ushortT* Q  = (ushortT*)(ws);
  ushortT* K  = (ushortT*)(ws + ((size_t)4 << 20));
  ushortT* Vt = (ushortT*)(ws + ((size_t)8 << 20));
  ushortT* Wt = (ushortT*)(ws + ((size_t)40 << 20));

  kprep<<<dim3(640), dim3(64), 0, stream>>>(Wg, Wf, Wh, Wt);
  kproj<<<dim3(10, 512), dim3(256), 0, stream>>>(x, Wt, bg, bfv, bh, Q, K, Vt);
  kattn<<<dim3(512), dim3(512), 0, stream>>>(Q, K, Vt, x, gamma, out);
}